// Round 3
// baseline (1111.254 us; speedup 1.0000x reference)
//
#include <hip/hip_runtime.h>
#include <hip/hip_bf16.h>
#include <math.h>

// ---------------- problem constants ----------------
#define B_ROWS 4096
#define DZ     2048
#define DE     128
#define M_EXP  32
#define H_DIM  1024
#define NBIG   32768          // M_EXP * H_DIM
#define NEXTRA 256            // 128 gate + 3 base + 125 zero-pad
#define NTOT   (NBIG + NEXTRA)   // 33024 = 129 * 256
#define W1_LD  (DZ + DE)      // 2176
#define NKT    64             // K-tiles of 32

typedef _Float16 half8  __attribute__((ext_vector_type(8)));
typedef float    f32x16 __attribute__((ext_vector_type(16)));

#define AS1 __attribute__((address_space(1)))
#define AS3 __attribute__((address_space(3)))

__device__ __forceinline__ void async_copy16(const void* g, void* l) {
  __builtin_amdgcn_global_load_lds((const AS1 void*)g, (AS3 void*)l, 16, 0, 0);
}

__device__ __forceinline__ half8 cvt8(const float4& a, const float4& b) {
  half8 h = {(_Float16)a.x, (_Float16)a.y, (_Float16)a.z, (_Float16)a.w,
             (_Float16)b.x, (_Float16)b.y, (_Float16)b.z, (_Float16)b.w};
  return h;
}

// exact-GELU via A&S 7.1.26 erf (|eps| <= 1.5e-7)
__device__ __forceinline__ float gelu_f(float x) {
  float u = fabsf(x) * 0.70710678118654752f;
  float t = 1.0f / fmaf(0.3275911f, u, 1.0f);
  float poly = t * fmaf(t, fmaf(t, fmaf(t, fmaf(t, 1.061405429f, -1.453152027f),
                                        1.421413741f), -0.284496736f), 0.254829592f);
  float er = 1.0f - poly * __expf(-u * u);
  er = copysignf(er, x);
  return 0.5f * x * (1.0f + er);
}

// ---------------- z -> f16 ----------------
__global__ __launch_bounds__(256) void k_cvt_z(const float* __restrict__ z,
                                               _Float16* __restrict__ zh) {
  long i = ((long)blockIdx.x * 256 + threadIdx.x) * 8;
  float4 a = *(const float4*)(z + i);
  float4 b = *(const float4*)(z + i + 4);
  *(half8*)(zh + i) = cvt8(a, b);
}

// ---------------- W1 z-part -> f16 packed rows; tail -> hbias = E.W1e + b1 ----------------
__global__ __launch_bounds__(256) void k_cvt_w1(const float* __restrict__ W1,
                                                const float* __restrict__ E,
                                                const float* __restrict__ b1,
                                                _Float16* __restrict__ W1h,
                                                float* __restrict__ hbias) {
  const long n = blockIdx.x;        // 0..32767
  const int  t = threadIdx.x;       // 256
  const float* src = W1 + n * W1_LD;
  float4 a = *(const float4*)(src + t * 8);
  float4 b = *(const float4*)(src + t * 8 + 4);
  *(half8*)(W1h + n * DZ + t * 8) = cvt8(a, b);
  if (t < 32) {
    int m = (int)(n >> 10);
    float4 w = *(const float4*)(src + DZ + t * 4);
    float4 e = *(const float4*)(E + m * DE + t * 4);
    float p = w.x * e.x + w.y * e.y + w.z * e.z + w.w * e.w;
    p += __shfl_xor(p, 16);
    p += __shfl_xor(p, 8);
    p += __shfl_xor(p, 4);
    p += __shfl_xor(p, 2);
    p += __shfl_xor(p, 1);
    if (t == 0) hbias[n] = p + b1[n];
  }
}

// ---------------- gate_W / base_W -> f16 rows appended; pad rows zeroed ----------------
__global__ __launch_bounds__(256) void k_cvt_small(const float* __restrict__ gate_W,
                                                   const float* __restrict__ base_W,
                                                   _Float16* __restrict__ W1h) {
  int r = blockIdx.x;               // 0..255
  int t = threadIdx.x;
  const float* src = nullptr;
  if (r < 128)       src = gate_W + (long)r * DZ;
  else if (r < 131)  src = base_W + (long)(r - 128) * DZ;
  _Float16* dst = W1h + (long)(NBIG + r) * DZ + t * 8;
  if (src) {
    float4 a = *(const float4*)(src + t * 8);
    float4 b = *(const float4*)(src + t * 8 + 4);
    *(half8*)dst = cvt8(a, b);
  } else {
    half8 zv = {(_Float16)0, (_Float16)0, (_Float16)0, (_Float16)0,
                (_Float16)0, (_Float16)0, (_Float16)0, (_Float16)0};
    *(half8*)dst = zv;
  }
}

// ============ 256x256 GEMM, ring-4 LDS (BK=32), reg-set double-buffered frags ============
// 8 waves (2Mx4N), each 128x64 out via 4x2 mfma_32x32x16_f16 tiles.
// Phase: BAR; stage(2 gload_lds for tile t+3); vmcnt(6); preload next-kk frags (6 ds_read);
//        sched_barrier; setprio(1); 8 MFMA; setprio(0).
// Certify slack = 4 phases; frag-read slack = 1 phase.
__global__ __launch_bounds__(512, 2) void k_gemm256(const _Float16* __restrict__ A,   // zh
                                                    const _Float16* __restrict__ Bm,  // W1h
                                                    const float* __restrict__ hbias,  // [NBIG]
                                                    const float* __restrict__ W2,     // [M,3,H]
                                                    float* __restrict__ Lout,         // [B,96] atomic
                                                    float* __restrict__ qraw) {       // [B,256]
  __shared__ _Float16 sm[4][16384];   // [buf][A:0..8191 | B:8192..16383], 128 KiB

  // XCD-aware bijective swizzle: 2064 blocks = 8 * 258
  int flat = blockIdx.y * gridDim.x + blockIdx.x;
  int wg   = (flat & 7) * 258 + (flat >> 3);
  const int tN = wg % 129;
  const int tM = wg / 129;

  const int tid = threadIdx.x;
  const int w = tid >> 6, l = tid & 63;
  const int wm = w >> 2, wn = w & 3;       // wave grid 2x4
  const int l31 = l & 31, hi = l >> 5;

  // ---- staging pointers (linear LDS dest, inverse-swizzled global src) ----
  const int r0   = tid >> 2;               // row 0..127 (first granule)
  const int sswz = ((tid & 3) ^ (r0 & 3)) * 8;
  const _Float16* pA0 = A  + (long)(tM * 256 + r0) * DZ + sswz;
  const _Float16* pB0 = Bm + (long)(tN * 256 + r0) * DZ + sswz;

#define STAGE(bq, isB, ktv) do { \
    const _Float16* _p = ((isB) ? pB0 : pA0) + (ktv) * 32; \
    _Float16* _d = &sm[bq][((isB) ? 8192 : 0) + (tid << 3)]; \
    async_copy16(_p, _d); \
    async_copy16(_p + 128 * DZ, _d + 4096); \
  } while (0)

  // ---- fragment read addresses (swizzled, bank-balanced) ----
  const int rA = (wm * 128 + l31) * 32;
  const int rB = 8192 + (wn * 64 + l31) * 32;
  const int adrA0 = rA + ((hi       ^ (l31 & 3)) * 8);
  const int adrA1 = rA + (((2 + hi) ^ (l31 & 3)) * 8);
  const int adrB0 = rB + ((hi       ^ (l31 & 3)) * 8);
  const int adrB1 = rB + (((2 + hi) ^ (l31 & 3)) * 8);

  half8 aA[4], bA[2], aB[4], bB[2];
  f32x16 acc[4][2];
#pragma unroll
  for (int i = 0; i < 4; ++i)
#pragma unroll
    for (int j = 0; j < 2; ++j)
#pragma unroll
      for (int r = 0; r < 16; ++r) acc[i][j][r] = 0.f;

#define READ6(a_, b_, bq, K) do { \
    const _Float16* _ba = &sm[bq][0]; \
    _Pragma("unroll") for (int _i = 0; _i < 4; ++_i) a_[_i] = *(const half8*)(_ba + adrA##K + _i * 1024); \
    _Pragma("unroll") for (int _j = 0; _j < 2; ++_j) b_[_j] = *(const half8*)(_ba + adrB##K + _j * 1024); \
  } while (0)

#define MFMA8(a_, b_) do { __builtin_amdgcn_s_setprio(1); \
    _Pragma("unroll") for (int _i = 0; _i < 4; ++_i) \
    _Pragma("unroll") for (int _j = 0; _j < 2; ++_j) \
      acc[_i][_j] = __builtin_amdgcn_mfma_f32_32x32x16_f16(a_[_i], b_[_j], acc[_i][_j], 0, 0, 0); \
    __builtin_amdgcn_s_setprio(0); } while (0)

#define BAR() do { asm volatile("" ::: "memory"); __builtin_amdgcn_s_barrier(); asm volatile("" ::: "memory"); } while (0)
#define SBAR0 __builtin_amdgcn_sched_barrier(0)
#define VMCNT8 asm volatile("s_waitcnt vmcnt(8)" ::: "memory")
#define VMCNT6 asm volatile("s_waitcnt vmcnt(6)" ::: "memory")
#define VMCNT4 asm volatile("s_waitcnt vmcnt(4)" ::: "memory")
#define VMCNT0 asm volatile("s_waitcnt vmcnt(0)" ::: "memory")

  // phase .0 of tile (buf q): MFMA setA(kk0), preload kk1 -> setB
#define PH0(q, VM_STMT, STAGE_STMT) do { BAR(); STAGE_STMT; VM_STMT; \
    READ6(aB, bB, q, 1); SBAR0; MFMA8(aA, bA); } while (0)
  // phase .1 of tile (buf q): MFMA setB(kk1), preload next tile kk0 -> setA
#define PH1(q, STAGE_STMT) do { BAR(); STAGE_STMT; VMCNT6; \
    READ6(aA, bA, ((q) + 1) & 3, 0); SBAR0; MFMA8(aB, bB); } while (0)

  // ---- prologue: stage tiles 0,1,2 (12 loads); certify t0; preload t0.kk0 ----
  STAGE(0, 0, 0); STAGE(0, 1, 0);
  STAGE(1, 0, 1); STAGE(1, 1, 1);
  STAGE(2, 0, 2); STAGE(2, 1, 2);
  VMCNT8;
  BAR();
  READ6(aA, bA, 0, 0);

  // ---- main loop: tiles 0..59 ----
  for (int n = 0; n < 15; ++n) {
    const int kb = 4 * n;
    PH0(0, VMCNT6, STAGE(3, 0, kb + 3)); PH1(0, STAGE(3, 1, kb + 3));
    PH0(1, VMCNT6, STAGE(0, 0, kb + 4)); PH1(1, STAGE(0, 1, kb + 4));
    PH0(2, VMCNT6, STAGE(1, 0, kb + 5)); PH1(2, STAGE(1, 1, kb + 5));
    PH0(3, VMCNT6, STAGE(2, 0, kb + 6)); PH1(3, STAGE(2, 1, kb + 6));
  }
  // ---- tail: tiles 60..63 ----
  PH0(0, VMCNT6, STAGE(3, 0, 63)); PH1(0, STAGE(3, 1, 63));
  PH0(1, VMCNT4, (void)0);         PH1(1, (void)0);
  PH0(2, VMCNT0, (void)0);         PH1(2, (void)0);
  PH0(3, (void)0, (void)0);
  BAR(); SBAR0; MFMA8(aB, bB);

  // ---- epilogue ----
  // C/D 32x32 layout: col = l&31, row = (r&3) + 8*(r>>2) + 4*hi
  if (tN < 128) {
    const int m = tN >> 2;                    // 4 N-tiles of 256 per expert
    const int hbase = (tN & 3) * 256 + wn * 64;
    float hb[2], w2v[3][2];
#pragma unroll
    for (int j = 0; j < 2; ++j) {
      int hc = hbase + j * 32 + l31;          // col within expert (0..1023)
      hb[j] = hbias[tN * 256 + wn * 64 + j * 32 + l31];
#pragma unroll
      for (int o = 0; o < 3; ++o) w2v[o][j] = W2[((long)m * 3 + o) * H_DIM + hc];
    }
#pragma unroll
    for (int i = 0; i < 4; ++i) {
      const int growb = tM * 256 + wm * 128 + i * 32 + 4 * hi;
#pragma unroll
      for (int r = 0; r < 16; ++r) {
        int grow = growb + (r & 3) + 8 * (r >> 2);
        float g0 = gelu_f(acc[i][0][r] + hb[0]);
        float g1 = gelu_f(acc[i][1][r] + hb[1]);
#pragma unroll
        for (int o = 0; o < 3; ++o) {
          float p = g0 * w2v[o][0] + g1 * w2v[o][1];
          p += __shfl_xor(p, 1);
          p += __shfl_xor(p, 2);
          p += __shfl_xor(p, 4);
          p += __shfl_xor(p, 8);
          p += __shfl_xor(p, 16);
          if (l31 == o) atomicAdd(&Lout[(long)grow * 96 + m * 3 + o], p);
        }
      }
    }
  } else {
    // raw gate/base pre-activations (global cols 32768..33023)
#pragma unroll
    for (int i = 0; i < 4; ++i) {
      const int growb = tM * 256 + wm * 128 + i * 32 + 4 * hi;
#pragma unroll
      for (int r = 0; r < 16; ++r) {
        int grow = growb + (r & 3) + 8 * (r >> 2);
        int c0 = wn * 64 + l31;
        qraw[(long)grow * 256 + c0]      = acc[i][0][r];
        qraw[(long)grow * 256 + c0 + 32] = acc[i][1][r];
      }
    }
  }
}

// ---------------- post: q normalize, sims, L += base + b2 ----------------
__global__ __launch_bounds__(128) void k_post(const float* __restrict__ qraw,
                                              const float* __restrict__ gate_b,
                                              const float* __restrict__ base_b,
                                              const float* __restrict__ E,
                                              const float* __restrict__ b2,
                                              float* __restrict__ out) {
  const int b = blockIdx.x;
  const int t = threadIdx.x;          // 128
  __shared__ float qs[DE];
  __shared__ float invE[M_EXP];
  __shared__ float wsum[2];
  __shared__ float pA[M_EXP], pB[M_EXP];

  if (t < 32) {
    float ss = 0.f;
    const float* er = E + t * DE;
    for (int e = 0; e < DE; ++e) { float v = er[e]; ss += v * v; }
    invE[t] = 1.0f / fmaxf(sqrtf(ss), 1e-12f);
  }

  float val = qraw[(long)b * 256 + t] + gate_b[t];
  float ss = val * val;
  ss += __shfl_xor(ss, 1);  ss += __shfl_xor(ss, 2);  ss += __shfl_xor(ss, 4);
  ss += __shfl_xor(ss, 8);  ss += __shfl_xor(ss, 16); ss += __shfl_xor(ss, 32);
  if ((t & 63) == 0) wsum[t >> 6] = ss;
  __syncthreads();
  float inv = 1.0f / fmaxf(sqrtf(wsum[0] + wsum[1]), 1e-12f);
  qs[t] = val * inv;
  __syncthreads();

  {
    int m = t & 31, hf = t >> 5;
    const float* er = E + m * DE + hf * 32;
    const float* qq = qs + hf * 32;
    float p = 0.f;
#pragma unroll
    for (int e = 0; e < 32; ++e) p += qq[e] * er[e];
    p += __shfl_xor(p, 32);
    if (t < 32) pA[m] = p;
    else if (t >= 64 && t < 96) pB[m] = p;
    __syncthreads();
    if (t < 32) out[(long)B_ROWS * 96 + (long)b * 32 + t] = (pA[t] + pB[t]) * invE[t];
  }

  if (t < 96) {
    int o = t % 3;
    float bv = qraw[(long)b * 256 + 128 + o] + base_b[o];
    out[(long)b * 96 + t] += bv + b2[t];
  }
}

// ---------------- launch ----------------
extern "C" void kernel_launch(void* const* d_in, const int* in_sizes, int n_in,
                              void* d_out, int out_size, void* d_ws, size_t ws_size,
                              hipStream_t stream) {
  const float* z      = (const float*)d_in[0];
  const float* base_W = (const float*)d_in[1];
  const float* base_b = (const float*)d_in[2];
  const float* gate_W = (const float*)d_in[3];
  const float* gate_b = (const float*)d_in[4];
  const float* E      = (const float*)d_in[5];
  const float* W1     = (const float*)d_in[6];
  const float* b1     = (const float*)d_in[7];
  const float* W2     = (const float*)d_in[8];
  const float* b2     = (const float*)d_in[9];
  float* out = (float*)d_out;

  char* ws = (char*)d_ws;
  const size_t off_zh    = 0;                                   // B*DZ*2
  const size_t off_w1h   = off_zh  + (size_t)B_ROWS * DZ * 2;   // NTOT*DZ*2
  const size_t off_hbias = off_w1h + (size_t)NTOT * DZ * 2;     // NBIG*4
  const size_t off_qraw  = off_hbias + (size_t)NBIG * 4;        // B*256*4
  _Float16* zh    = (_Float16*)(ws + off_zh);
  _Float16* W1h   = (_Float16*)(ws + off_w1h);
  float*    hbias = (float*)(ws + off_hbias);
  float*    qraw  = (float*)(ws + off_qraw);

  // L must start at 0 every call (epilogue atomically accumulates into it)
  hipMemsetAsync(d_out, 0, (size_t)B_ROWS * 96 * sizeof(float), stream);

  k_cvt_z<<<(B_ROWS * DZ) / (256 * 8), 256, 0, stream>>>(z, zh);
  k_cvt_w1<<<NBIG, 256, 0, stream>>>(W1, E, b1, W1h, hbias);
  k_cvt_small<<<NEXTRA, 256, 0, stream>>>(gate_W, base_W, W1h);
  k_gemm256<<<dim3(129, 16), 512, 0, stream>>>(zh, W1h, hbias, W2, out, qraw);
  k_post<<<B_ROWS, 128, 0, stream>>>(qraw, gate_b, base_b, E, b2, out);
}

// Round 4
// 864.860 us; speedup vs baseline: 1.2849x; 1.2849x over previous
//
#include <hip/hip_runtime.h>
#include <hip/hip_bf16.h>
#include <math.h>

// ---------------- problem constants ----------------
#define B_ROWS 4096
#define DZ     2048
#define DE     128
#define M_EXP  32
#define H_DIM  1024
#define NBIG   32768          // M_EXP * H_DIM
#define NEXTRA 256            // 128 gate + 3 base + 125 zero-pad
#define NTOT   (NBIG + NEXTRA)   // 33024 = 129 * 256
#define W1_LD  (DZ + DE)      // 2176

typedef _Float16 half8  __attribute__((ext_vector_type(8)));
typedef float    f32x16 __attribute__((ext_vector_type(16)));

#define AS1 __attribute__((address_space(1)))
#define AS3 __attribute__((address_space(3)))

__device__ __forceinline__ void async_copy16(const void* g, void* l) {
  __builtin_amdgcn_global_load_lds((const AS1 void*)g, (AS3 void*)l, 16, 0, 0);
}

__device__ __forceinline__ half8 cvt8(const float4& a, const float4& b) {
  half8 h = {(_Float16)a.x, (_Float16)a.y, (_Float16)a.z, (_Float16)a.w,
             (_Float16)b.x, (_Float16)b.y, (_Float16)b.z, (_Float16)b.w};
  return h;
}

// exact-GELU via A&S 7.1.26 erf (|eps| <= 1.5e-7)
__device__ __forceinline__ float gelu_f(float x) {
  float u = fabsf(x) * 0.70710678118654752f;
  float t = 1.0f / fmaf(0.3275911f, u, 1.0f);
  float poly = t * fmaf(t, fmaf(t, fmaf(t, fmaf(t, 1.061405429f, -1.453152027f),
                                        1.421413741f), -0.284496736f), 0.254829592f);
  float er = 1.0f - poly * __expf(-u * u);
  er = copysignf(er, x);
  return 0.5f * x * (1.0f + er);
}

// ---------------- z -> f16 ----------------
__global__ __launch_bounds__(256) void k_cvt_z(const float* __restrict__ z,
                                               _Float16* __restrict__ zh) {
  long i = ((long)blockIdx.x * 256 + threadIdx.x) * 8;
  float4 a = *(const float4*)(z + i);
  float4 b = *(const float4*)(z + i + 4);
  *(half8*)(zh + i) = cvt8(a, b);
}

// ---------------- W1 z-part -> f16 packed rows; tail -> hbias = E.W1e + b1 ----------------
__global__ __launch_bounds__(256) void k_cvt_w1(const float* __restrict__ W1,
                                                const float* __restrict__ E,
                                                const float* __restrict__ b1,
                                                _Float16* __restrict__ W1h,
                                                float* __restrict__ hbias) {
  const long n = blockIdx.x;        // 0..32767
  const int  t = threadIdx.x;       // 256
  const float* src = W1 + n * W1_LD;
  float4 a = *(const float4*)(src + t * 8);
  float4 b = *(const float4*)(src + t * 8 + 4);
  *(half8*)(W1h + n * DZ + t * 8) = cvt8(a, b);
  if (t < 32) {
    int m = (int)(n >> 10);
    float4 w = *(const float4*)(src + DZ + t * 4);
    float4 e = *(const float4*)(E + m * DE + t * 4);
    float p = w.x * e.x + w.y * e.y + w.z * e.z + w.w * e.w;
    p += __shfl_xor(p, 16);
    p += __shfl_xor(p, 8);
    p += __shfl_xor(p, 4);
    p += __shfl_xor(p, 2);
    p += __shfl_xor(p, 1);
    if (t == 0) hbias[n] = p + b1[n];
  }
}

// ---------------- gate_W / base_W -> f16 rows appended; pad rows zeroed ----------------
__global__ __launch_bounds__(256) void k_cvt_small(const float* __restrict__ gate_W,
                                                   const float* __restrict__ base_W,
                                                   _Float16* __restrict__ W1h) {
  int r = blockIdx.x;               // 0..255
  int t = threadIdx.x;
  const float* src = nullptr;
  if (r < 128)       src = gate_W + (long)r * DZ;
  else if (r < 131)  src = base_W + (long)(r - 128) * DZ;
  _Float16* dst = W1h + (long)(NBIG + r) * DZ + t * 8;
  if (src) {
    float4 a = *(const float4*)(src + t * 8);
    float4 b = *(const float4*)(src + t * 8 + 4);
    *(half8*)dst = cvt8(a, b);
  } else {
    half8 zv = {(_Float16)0, (_Float16)0, (_Float16)0, (_Float16)0,
                (_Float16)0, (_Float16)0, (_Float16)0, (_Float16)0};
    *(half8*)dst = zv;
  }
}

// ============ 128x256 GEMM, ring-3 LDS (BK=32), 4 waves, 2 blocks/CU ============
// Wave (wm,wn) owns 64x128 out = 2x4 mfma_32x32x16_f16 tiles; acc 128 f32.
// Swizzle: granule (row,g) stored at slot s = g ^ ((row>>1)&3)  [parity-decorrelated,
// per-half-wave bank-balanced]. Phase = {stage; vmcnt; BAR; preload next frags (6 ds_read);
// sched_barrier; setprio(1); 8 MFMA; setprio(0)}. Ring-3: stage tile t+2 during t,
// certify t+1 at t.P1 with vmcnt(6) (slack 2 phases + cross-block overlap).
__global__ __launch_bounds__(256, 2) void k_gemm(const _Float16* __restrict__ A,   // zh
                                                 const _Float16* __restrict__ Bm,  // W1h
                                                 const float* __restrict__ hbias,  // [NBIG]
                                                 const float* __restrict__ W2,     // [M,3,H]
                                                 float* __restrict__ Lout,         // [B,96] atomic
                                                 float* __restrict__ qraw) {       // [B,256]
  __shared__ _Float16 sm[3][12288];   // [buf][A:0..4095 | B:4096..12287], 72 KiB

  // XCD-aware bijective swizzle: 4128 blocks = 8 * 516
  int flat = blockIdx.y * gridDim.x + blockIdx.x;
  int wg   = (flat & 7) * 516 + (flat >> 3);
  const int tN = wg >> 5;           // 0..128  (B-panel shared by 32 consecutive wg)
  const int tM = wg & 31;           // 0..31

  const int tid = threadIdx.x;
  const int w = tid >> 6, l = tid & 63;
  const int wm = w >> 1, wn = w & 1;       // wave grid 2x2
  const int l31 = l & 31, hi = l >> 5;

  // ---- staging source pointers (linear LDS dest, inverse-swizzled global src) ----
  const int srow = tid >> 2;               // 0..63
  const int sg   = ((tid & 3) ^ ((srow >> 1) & 3)) * 8;   // swizzled k-granule (elems)
  const _Float16* pA = A  + (long)(tM * 128 + srow) * DZ + sg;
  const _Float16* pB = Bm + (long)(tN * 256 + srow) * DZ + sg;

#define STAGE_A(sb, kt) do { \
    async_copy16(pA + (kt) * 32,            &sm[sb][tid * 8]); \
    async_copy16(pA + 64 * DZ + (kt) * 32,  &sm[sb][2048 + tid * 8]); } while (0)
#define STAGE_B0(sb, kt) do { \
    async_copy16(pB + (kt) * 32,            &sm[sb][4096 + tid * 8]); \
    async_copy16(pB + 64 * DZ + (kt) * 32,  &sm[sb][6144 + tid * 8]); } while (0)
#define STAGE_B1(sb, kt) do { \
    async_copy16(pB + 128 * DZ + (kt) * 32, &sm[sb][8192 + tid * 8]); \
    async_copy16(pB + 192 * DZ + (kt) * 32, &sm[sb][10240 + tid * 8]); } while (0)

  // ---- fragment read offsets (halfs) ----
  const int offA  = (wm * 64 + l31) * 32;            // A rows
  const int offB  = 4096 + (wn * 128 + l31) * 32;    // B rows
  const int offK0 = (hi ^ ((l31 >> 1) & 3)) * 8;     // kk0 slot; kk1 = offK0 ^ 16

  half8 aA[2], bA[4], aB[2], bB[4];
  f32x16 acc[2][4];
#pragma unroll
  for (int i = 0; i < 2; ++i)
#pragma unroll
    for (int j = 0; j < 4; ++j)
#pragma unroll
      for (int r = 0; r < 16; ++r) acc[i][j][r] = 0.f;

#define READ6(a_, b_, bq, kk) do { \
    const int _ok = (kk) ? (offK0 ^ 16) : offK0; \
    const _Float16* _s = &sm[bq][0]; \
    a_[0] = *(const half8*)(_s + offA + _ok); \
    a_[1] = *(const half8*)(_s + offA + 1024 + _ok); \
    _Pragma("unroll") for (int _j = 0; _j < 4; ++_j) \
      b_[_j] = *(const half8*)(_s + offB + _j * 1024 + _ok); \
  } while (0)

#define MFMA8(a_, b_) do { __builtin_amdgcn_s_setprio(1); \
    _Pragma("unroll") for (int _i = 0; _i < 2; ++_i) \
    _Pragma("unroll") for (int _j = 0; _j < 4; ++_j) \
      acc[_i][_j] = __builtin_amdgcn_mfma_f32_32x32x16_f16(a_[_i], b_[_j], acc[_i][_j], 0, 0, 0); \
    __builtin_amdgcn_s_setprio(0); } while (0)

#define BAR() do { asm volatile("" ::: "memory"); __builtin_amdgcn_s_barrier(); asm volatile("" ::: "memory"); } while (0)
#define SBAR0 __builtin_amdgcn_sched_barrier(0)
#define VMCNT6 asm volatile("s_waitcnt vmcnt(6)" ::: "memory")
#define VMCNT0 asm volatile("s_waitcnt vmcnt(0)" ::: "memory")

  // phase 0 of tile t (buf bq): stage A+B0 of t+2; preload kk1 of t; MFMA kk0
#define PH0S(bq, sb, kt) do { STAGE_A(sb, kt); STAGE_B0(sb, kt); BAR(); \
    READ6(aB, bB, bq, 1); SBAR0; MFMA8(aA, bA); } while (0)
  // phase 1 of tile t: stage B1 of t+2; certify t+1; preload kk0 of t+1; MFMA kk1
#define PH1S(bqn, sb, kt) do { STAGE_B1(sb, kt); VMCNT6; BAR(); \
    READ6(aA, bA, bqn, 0); SBAR0; MFMA8(aB, bB); } while (0)

  // ---- prologue: stage tiles 0,1 (12 loads); certify t0; preload t0.kk0 ----
  STAGE_A(0, 0); STAGE_B0(0, 0); STAGE_B1(0, 0);
  STAGE_A(1, 1); STAGE_B0(1, 1); STAGE_B1(1, 1);
  VMCNT6;
  BAR();
  READ6(aA, bA, 0, 0);

  // ---- main loop: tiles 0..59, 20 iters x 3 ----
  for (int n = 0; n < 20; ++n) {
    const int t3 = 3 * n;
    PH0S(0, 2, t3 + 2); PH1S(1, 2, t3 + 2);
    PH0S(1, 0, t3 + 3); PH1S(2, 0, t3 + 3);
    PH0S(2, 1, t3 + 4); PH1S(0, 1, t3 + 4);
  }
  // ---- tail: tiles 60..63 ----
  PH0S(0, 2, 62); PH1S(1, 2, 62);
  PH0S(1, 0, 63); PH1S(2, 0, 63);
  // t=62 (buf2, no stage)
  BAR(); READ6(aB, bB, 2, 1); SBAR0; MFMA8(aA, bA);
  VMCNT0; BAR(); READ6(aA, bA, 0, 0); SBAR0; MFMA8(aB, bB);
  // t=63 (buf0, no stage)
  BAR(); READ6(aB, bB, 0, 1); SBAR0; MFMA8(aA, bA);
  MFMA8(aB, bB);

  // ---- epilogue ----
  // C/D 32x32 layout: col = l31, row = (r&3) + 8*(r>>2) + 4*hi
  if (tN < 128) {
    const int m = tN >> 2;                    // 4 N-tiles of 256 per expert
    float hb[4], w2v[3][4];
#pragma unroll
    for (int j = 0; j < 4; ++j) {
      int gcol = tN * 256 + wn * 128 + j * 32 + l31;   // global big col
      int he   = gcol & (H_DIM - 1);                   // col within expert
      hb[j] = hbias[gcol];
#pragma unroll
      for (int o = 0; o < 3; ++o) w2v[o][j] = W2[((long)m * 3 + o) * H_DIM + he];
    }
#pragma unroll
    for (int i = 0; i < 2; ++i) {
      const int growb = tM * 128 + wm * 64 + i * 32 + 4 * hi;
#pragma unroll
      for (int r = 0; r < 16; ++r) {
        int grow = growb + (r & 3) + 8 * (r >> 2);
        float g0 = gelu_f(acc[i][0][r] + hb[0]);
        float g1 = gelu_f(acc[i][1][r] + hb[1]);
        float g2 = gelu_f(acc[i][2][r] + hb[2]);
        float g3 = gelu_f(acc[i][3][r] + hb[3]);
#pragma unroll
        for (int o = 0; o < 3; ++o) {
          float p = g0 * w2v[o][0] + g1 * w2v[o][1] + g2 * w2v[o][2] + g3 * w2v[o][3];
          p += __shfl_xor(p, 1);
          p += __shfl_xor(p, 2);
          p += __shfl_xor(p, 4);
          p += __shfl_xor(p, 8);
          p += __shfl_xor(p, 16);
          if (l31 == o) atomicAdd(&Lout[(long)grow * 96 + m * 3 + o], p);
        }
      }
    }
  } else {
    // raw gate/base pre-activations (global cols 32768..33023)
#pragma unroll
    for (int i = 0; i < 2; ++i) {
      const int growb = tM * 128 + wm * 64 + i * 32 + 4 * hi;
#pragma unroll
      for (int r = 0; r < 16; ++r) {
        int grow = growb + (r & 3) + 8 * (r >> 2);
        int c0 = wn * 128 + l31;
#pragma unroll
        for (int j = 0; j < 4; ++j)
          qraw[(long)grow * 256 + c0 + j * 32] = acc[i][j][r];
      }
    }
  }
}

// ---------------- post: q normalize, sims, L += base + b2 ----------------
__global__ __launch_bounds__(128) void k_post(const float* __restrict__ qraw,
                                              const float* __restrict__ gate_b,
                                              const float* __restrict__ base_b,
                                              const float* __restrict__ E,
                                              const float* __restrict__ b2,
                                              float* __restrict__ out) {
  const int b = blockIdx.x;
  const int t = threadIdx.x;          // 128
  __shared__ float qs[DE];
  __shared__ float invE[M_EXP];
  __shared__ float wsum[2];
  __shared__ float pA[M_EXP], pB[M_EXP];

  if (t < 32) {
    float ss = 0.f;
    const float* er = E + t * DE;
    for (int e = 0; e < DE; ++e) { float v = er[e]; ss += v * v; }
    invE[t] = 1.0f / fmaxf(sqrtf(ss), 1e-12f);
  }

  float val = qraw[(long)b * 256 + t] + gate_b[t];
  float ss = val * val;
  ss += __shfl_xor(ss, 1);  ss += __shfl_xor(ss, 2);  ss += __shfl_xor(ss, 4);
  ss += __shfl_xor(ss, 8);  ss += __shfl_xor(ss, 16); ss += __shfl_xor(ss, 32);
  if ((t & 63) == 0) wsum[t >> 6] = ss;
  __syncthreads();
  float inv = 1.0f / fmaxf(sqrtf(wsum[0] + wsum[1]), 1e-12f);
  qs[t] = val * inv;
  __syncthreads();

  {
    int m = t & 31, hf = t >> 5;
    const float* er = E + m * DE + hf * 32;
    const float* qq = qs + hf * 32;
    float p = 0.f;
#pragma unroll
    for (int e = 0; e < 32; ++e) p += qq[e] * er[e];
    p += __shfl_xor(p, 32);
    if (t < 32) pA[m] = p;
    else if (t >= 64 && t < 96) pB[m] = p;
    __syncthreads();
    if (t < 32) out[(long)B_ROWS * 96 + (long)b * 32 + t] = (pA[t] + pB[t]) * invE[t];
  }

  if (t < 96) {
    int o = t % 3;
    float bv = qraw[(long)b * 256 + 128 + o] + base_b[o];
    out[(long)b * 96 + t] += bv + b2[t];
  }
}

// ---------------- launch ----------------
extern "C" void kernel_launch(void* const* d_in, const int* in_sizes, int n_in,
                              void* d_out, int out_size, void* d_ws, size_t ws_size,
                              hipStream_t stream) {
  const float* z      = (const float*)d_in[0];
  const float* base_W = (const float*)d_in[1];
  const float* base_b = (const float*)d_in[2];
  const float* gate_W = (const float*)d_in[3];
  const float* gate_b = (const float*)d_in[4];
  const float* E      = (const float*)d_in[5];
  const float* W1     = (const float*)d_in[6];
  const float* b1     = (const float*)d_in[7];
  const float* W2     = (const float*)d_in[8];
  const float* b2     = (const float*)d_in[9];
  float* out = (float*)d_out;

  char* ws = (char*)d_ws;
  const size_t off_zh    = 0;                                   // B*DZ*2
  const size_t off_w1h   = off_zh  + (size_t)B_ROWS * DZ * 2;   // NTOT*DZ*2
  const size_t off_hbias = off_w1h + (size_t)NTOT * DZ * 2;     // NBIG*4
  const size_t off_qraw  = off_hbias + (size_t)NBIG * 4;        // B*256*4
  _Float16* zh    = (_Float16*)(ws + off_zh);
  _Float16* W1h   = (_Float16*)(ws + off_w1h);
  float*    hbias = (float*)(ws + off_hbias);
  float*    qraw  = (float*)(ws + off_qraw);

  // L must start at 0 every call (epilogue atomically accumulates into it)
  hipMemsetAsync(d_out, 0, (size_t)B_ROWS * 96 * sizeof(float), stream);

  k_cvt_z<<<(B_ROWS * DZ) / (256 * 8), 256, 0, stream>>>(z, zh);
  k_cvt_w1<<<NBIG, 256, 0, stream>>>(W1, E, b1, W1h, hbias);
  k_cvt_small<<<NEXTRA, 256, 0, stream>>>(gate_W, base_W, W1h);
  k_gemm<<<dim3(129, 32), 256, 0, stream>>>(zh, W1h, hbias, W2, out, qraw);
  k_post<<<B_ROWS, 128, 0, stream>>>(qraw, gate_b, base_b, E, b2, out);
}